// Round 4
// baseline (478.100 us; speedup 1.0000x reference)
//
#include <hip/hip_runtime.h>
#include <hip/hip_bf16.h>
#include <cstdint>
#include <cstddef>

#define BB 16
#define NN 128
#define MM 1024
#define DN 512
#define DE 256
#define PP 512

typedef __attribute__((ext_vector_type(8))) short s16x8;
typedef __attribute__((ext_vector_type(4))) float f32x4;
typedef __attribute__((ext_vector_type(4))) unsigned short u16x4;

__device__ __forceinline__ unsigned short f2b(float f) {
    __hip_bfloat16 h = __float2bfloat16(f);
    return *reinterpret_cast<unsigned short*>(&h);
}

// ---------------------------------------------------------------- K0:
// prep bf16 operands: W1t[768][512], WncT[256][512], WeT[128][256],
// We2T[128][256], W2catB[32][768] (block-diag zero-padded), b1cat, b2cat
__global__ __launch_bounds__(256) void k0_prep(
    const float* __restrict__ lrW1, const float* __restrict__ scrW1,
    const float* __restrict__ mrW1,
    const float* __restrict__ lrb1, const float* __restrict__ scrb1,
    const float* __restrict__ mrb1,
    const float* __restrict__ Wn, const float* __restrict__ Wn2,
    const float* __restrict__ We, const float* __restrict__ We2,
    const float* __restrict__ lrW2, const float* __restrict__ scrW2,
    const float* __restrict__ mrW2,
    const float* __restrict__ lrb2, const float* __restrict__ scrb2,
    const float* __restrict__ mrb2,
    ushort* __restrict__ W1t, ushort* __restrict__ WncT,
    ushort* __restrict__ WeT, ushort* __restrict__ We2T,
    ushort* __restrict__ W2catB,
    float* __restrict__ b1cat, float* __restrict__ b2cat)
{
    int blk = blockIdx.x;
    int t = threadIdx.x;
    if (blk < 768) {
        int h = blk >> 8, n = blk & 255;
        const float* W = (h == 0) ? lrW1 : (h == 1) ? scrW1 : mrW1;
        W1t[(size_t)blk * 512 + t]       = f2b(W[t * 256 + n]);
        W1t[(size_t)blk * 512 + t + 256] = f2b(W[(t + 256) * 256 + n]);
    } else if (blk == 768) {
        b1cat[t]       = lrb1[t];
        b1cat[256 + t] = scrb1[t];
        b1cat[512 + t] = mrb1[t];
    } else if (blk < 897) {            // WeT
        int n = blk - 769;
        WeT[(size_t)n * 256 + t] = f2b(We[t * 128 + n]);
    } else if (blk < 1153) {           // WncT
        int n = blk - 897;
        const float* W = (n < 128) ? Wn : Wn2;
        int c = n & 127;
        WncT[(size_t)n * 512 + t]       = f2b(W[t * 128 + c]);
        WncT[(size_t)n * 512 + t + 256] = f2b(W[(t + 256) * 128 + c]);
    } else if (blk < 1281) {           // We2T
        int n = blk - 1153;
        We2T[(size_t)n * 256 + t] = f2b(We2[t * 128 + n]);
    } else if (blk < 1313) {           // W2catB[o][768]
        int o = blk - 1281;
        for (int i = 0; i < 3; ++i) {
            int k = i * 256 + t;
            int seg = k >> 8, kk = k & 255;
            float v = 0.f;
            if (o < 9)       { if (seg == 0) v = lrW2[kk * 9 + o]; }
            else if (o < 15) { if (seg == 1) v = scrW2[kk * 6 + (o - 9)]; }
            else             { if (seg == 2) v = mrW2[kk * 17 + (o - 15)]; }
            W2catB[(size_t)o * 768 + k] = f2b(v);
        }
    } else {
        if (t < 32)
            b2cat[t] = (t < 9) ? lrb2[t] : (t < 15) ? scrb2[t - 9] : mrb2[t - 15];
    }
}

// ---------------------------------------------------------------- FPROJ:
//  route0 (blk   0..31 ): [Xmask]@[Wn|Wn2]  -> Yt bf16 (nb=0), Xp f32 (nb=1)
//  route1 (blk  32..159): [Eg*emask]@We     -> G1t bf16 [b][c][m]
//  route2 (blk 160..223): relu(ef_pair@We2) -> ci2 bf16 [8192][128]
__global__ __launch_bounds__(256) void fproj(
    const float* __restrict__ nf, const float* __restrict__ ef,
    const int* __restrict__ eidx, const int* __restrict__ opair,
    const int* __restrict__ nobj, const int* __restrict__ nedg,
    const ushort* __restrict__ WncT, const ushort* __restrict__ WeT,
    const ushort* __restrict__ We2T,
    ushort* __restrict__ Yt, float* __restrict__ Xp,
    ushort* __restrict__ G1t, ushort* __restrict__ ci2)
{
    __shared__ ushort As[128 * 32];
    __shared__ ushort Bs[128 * 32];
    __shared__ unsigned rowoff[128];
    __shared__ float    rowval[128];

    int blk = blockIdx.x;
    int route, mb, nb, K;
    const ushort* Bt;
    if (blk < 32)       { route = 0; mb = blk >> 1;  nb = blk & 1; K = 512; Bt = WncT; }
    else if (blk < 160) { route = 1; mb = blk - 32;  nb = 0;       K = 256; Bt = WeT;  }
    else                { route = 2; mb = blk - 160; nb = 0;       K = 256; Bt = We2T; }
    int row0 = mb * 128, col0 = nb * 128;
    int t = threadIdx.x;

    if (t < 128) {
        int r = row0 + t;
        unsigned off; float valid = 1.f;
        if (route == 0) {
            int b = r >> 7, i = r & 127;
            off = (unsigned)r * DN;
            valid = (i < nobj[b]) ? 1.f : 0.f;
        } else if (route == 1) {
            int b = r >> 10, m = r & 1023;
            int src = eidx[b * 2 * MM + m];
            int dst = eidx[b * 2 * MM + MM + m];
            off = (unsigned)((b * NN + src) * NN + dst) * DE;
            valid = (m < nedg[b]) ? 1.f : 0.f;
        } else {
            int b = r >> 9, p = r & 511;
            int i0 = opair[(b * PP + p) * 2];
            int i1 = opair[(b * PP + p) * 2 + 1];
            off = (unsigned)((b * NN + i0) * NN + i1) * DE;
        }
        rowoff[t] = off; rowval[t] = valid;
    }

    const float* Asrc = (route == 0) ? nf : ef;
    int lane = t & 63;
    int w    = t >> 6;
    int wr   = w >> 1, wc = w & 1;
    int arow = w * 32 + (lane >> 2);
    int ak   = (lane & 3) * 8;
    int qk   = (lane >> 4) * 8;
    int fr   = lane & 15;
    f32x4 acc[4][4];
    #pragma unroll
    for (int i = 0; i < 4; ++i)
        #pragma unroll
        for (int j = 0; j < 4; ++j) acc[i][j] = (f32x4){0.f, 0.f, 0.f, 0.f};

    for (int k0 = 0; k0 < K; k0 += 32) {
        __syncthreads();
        {
            unsigned o0 = rowoff[arow] + k0 + ak;
            unsigned o1 = rowoff[arow + 16] + k0 + ak;
            float m0 = rowval[arow], m1 = rowval[arow + 16];
            float4 a0 = *(const float4*)&Asrc[o0];
            float4 a1 = *(const float4*)&Asrc[o0 + 4];
            float4 b0 = *(const float4*)&Asrc[o1];
            float4 b1 = *(const float4*)&Asrc[o1 + 4];
            s16x8 pa, pb;
            pa[0]=f2b(a0.x*m0); pa[1]=f2b(a0.y*m0); pa[2]=f2b(a0.z*m0); pa[3]=f2b(a0.w*m0);
            pa[4]=f2b(a1.x*m0); pa[5]=f2b(a1.y*m0); pa[6]=f2b(a1.z*m0); pa[7]=f2b(a1.w*m0);
            pb[0]=f2b(b0.x*m1); pb[1]=f2b(b0.y*m1); pb[2]=f2b(b0.z*m1); pb[3]=f2b(b0.w*m1);
            pb[4]=f2b(b1.x*m1); pb[5]=f2b(b1.y*m1); pb[6]=f2b(b1.z*m1); pb[7]=f2b(b1.w*m1);
            *(s16x8*)&As[arow * 32 + ak]        = pa;
            *(s16x8*)&As[(arow + 16) * 32 + ak] = pb;
            *(s16x8*)&Bs[arow * 32 + ak] =
                *(const s16x8*)&Bt[(size_t)(col0 + arow) * K + k0 + ak];
            *(s16x8*)&Bs[(arow + 16) * 32 + ak] =
                *(const s16x8*)&Bt[(size_t)(col0 + arow + 16) * K + k0 + ak];
        }
        __syncthreads();
        s16x8 af[4], bfv[4];
        #pragma unroll
        for (int mi = 0; mi < 4; ++mi)
            af[mi] = *(const s16x8*)&As[(wr * 64 + mi * 16 + fr) * 32 + qk];
        #pragma unroll
        for (int ni = 0; ni < 4; ++ni)
            bfv[ni] = *(const s16x8*)&Bs[(wc * 64 + ni * 16 + fr) * 32 + qk];
        #pragma unroll
        for (int mi = 0; mi < 4; ++mi)
            #pragma unroll
            for (int ni = 0; ni < 4; ++ni)
                acc[mi][ni] = __builtin_amdgcn_mfma_f32_16x16x32_bf16(
                    af[mi], bfv[ni], acc[mi][ni], 0, 0, 0);
    }
    int crow = (lane >> 4) * 4;
    #pragma unroll
    for (int mi = 0; mi < 4; ++mi) {
        #pragma unroll
        for (int ni = 0; ni < 4; ++ni) {
            int c   = wc * 64 + ni * 16 + fr;       // 0..127 within tile
            int lr0 = wr * 64 + mi * 16 + crow;     // local row
            if (route == 0 && nb == 0) {
                u16x4 pk;
                #pragma unroll
                for (int rg = 0; rg < 4; ++rg) pk[rg] = f2b(acc[mi][ni][rg]);
                *(u16x4*)&Yt[(size_t)mb * 16384 + c * 128 + lr0] = pk;
            } else if (route == 0) {
                #pragma unroll
                for (int rg = 0; rg < 4; ++rg)
                    Xp[(size_t)(row0 + lr0 + rg) * 128 + c] = acc[mi][ni][rg];
            } else if (route == 1) {
                int r0 = row0 + lr0;
                int b1 = r0 >> 10, m0 = r0 & 1023;
                u16x4 pk;
                #pragma unroll
                for (int rg = 0; rg < 4; ++rg) pk[rg] = f2b(acc[mi][ni][rg]);
                *(u16x4*)&G1t[(size_t)b1 * 131072 + c * 1024 + m0] = pk;
            } else {
                #pragma unroll
                for (int rg = 0; rg < 4; ++rg)
                    ci2[(size_t)(row0 + lr0 + rg) * 128 + c] =
                        f2b(fmaxf(acc[mi][ni][rg], 0.f));
            }
        }
    }
}

// ---------------------------------------------------------------- K2M:
// h = relu(A @ Y) via MFMA (A = adj*mask + eye, exact in bf16).
// Writes node_emb[...,:128]; zeroes agg half. One block per batch.
__global__ __launch_bounds__(256) void k2m_gcn(
    const float* __restrict__ adj, const int* __restrict__ nobj,
    const ushort* __restrict__ Yt, float* __restrict__ node_emb)
{
    __shared__ ushort As[128 * 32];
    __shared__ ushort Bs[128 * 32];
    int b = blockIdx.x;
    int s = nobj[b];
    int t = threadIdx.x;
    int lane = t & 63, w = t >> 6, wr = w >> 1, wc = w & 1;
    int arow = w * 32 + (lane >> 2);
    int ak   = (lane & 3) * 8;
    int qk   = (lane >> 4) * 8, fr = lane & 15;
    f32x4 acc[4][4];
    #pragma unroll
    for (int i = 0; i < 4; ++i)
        #pragma unroll
        for (int j = 0; j < 4; ++j) acc[i][j] = (f32x4){0.f, 0.f, 0.f, 0.f};

    for (int k0 = 0; k0 < 128; k0 += 32) {
        __syncthreads();
        #pragma unroll
        for (int rr = 0; rr < 2; ++rr) {
            int i = arow + rr * 16;
            float rm = (i < s) ? 1.f : 0.f;
            const float* ar = adj + ((size_t)(b * NN + i)) * NN + k0 + ak;
            float4 a0 = *(const float4*)ar;
            float4 a1 = *(const float4*)(ar + 4);
            float vv[8] = {a0.x,a0.y,a0.z,a0.w,a1.x,a1.y,a1.z,a1.w};
            s16x8 pk;
            #pragma unroll
            for (int e = 0; e < 8; ++e) {
                int j = k0 + ak + e;
                float cm = (j < s) ? 1.f : 0.f;
                float v = vv[e] * rm * cm + ((j == i) ? rm : 0.f);
                pk[e] = (short)f2b(v);
            }
            *(s16x8*)&As[i * 32 + ak] = pk;
            *(s16x8*)&Bs[i * 32 + ak] =
                *(const s16x8*)&Yt[(size_t)b * 16384 + i * 128 + k0 + ak];
        }
        __syncthreads();
        s16x8 af[4], bfv[4];
        #pragma unroll
        for (int mi = 0; mi < 4; ++mi)
            af[mi] = *(const s16x8*)&As[(wr * 64 + mi * 16 + fr) * 32 + qk];
        #pragma unroll
        for (int ni = 0; ni < 4; ++ni)
            bfv[ni] = *(const s16x8*)&Bs[(wc * 64 + ni * 16 + fr) * 32 + qk];
        #pragma unroll
        for (int mi = 0; mi < 4; ++mi)
            #pragma unroll
            for (int ni = 0; ni < 4; ++ni)
                acc[mi][ni] = __builtin_amdgcn_mfma_f32_16x16x32_bf16(
                    af[mi], bfv[ni], acc[mi][ni], 0, 0, 0);
    }
    int crow = (lane >> 4) * 4;
    #pragma unroll
    for (int mi = 0; mi < 4; ++mi) {
        #pragma unroll
        for (int ni = 0; ni < 4; ++ni) {
            int gc = wc * 64 + ni * 16 + fr;
            int i0 = wr * 64 + mi * 16 + crow;
            #pragma unroll
            for (int rg = 0; rg < 4; ++rg) {
                node_emb[(size_t)(b * NN + i0 + rg) * 256 + gc] =
                    fmaxf(acc[mi][ni][rg], 0.f);
                node_emb[(size_t)(b * NN + i0 + rg) * 256 + 128 + gc] = 0.f;
            }
        }
    }
}

// ---------------------------------------------------------------- LGEMM:
// g = relu(L @ G1) via dense MFMA (L binary+eye, exact bf16);
// scatter-add g into node_emb agg half. 64-row tiles, 256 blocks.
__global__ __launch_bounds__(256) void lgemm(
    const float* __restrict__ la, const ushort* __restrict__ G1t,
    const int* __restrict__ eidx, const int* __restrict__ nedg,
    float* __restrict__ node_emb)
{
    __shared__ ushort As[64 * 32];
    __shared__ ushort Bs[128 * 32];
    __shared__ int srcs[64];
    int b  = blockIdx.x >> 4;
    int mt = blockIdx.x & 15;
    int row0 = mt * 64;
    int se = nedg[b];
    int t = threadIdx.x;
    if (t < 64) srcs[t] = eidx[b * 2 * MM + row0 + t];
    int lane = t & 63, w = t >> 6, wr = w >> 1, wc = w & 1;
    int arow = t >> 2;          // 0..63
    int ak   = (t & 3) * 8;
    int qk   = (lane >> 4) * 8, fr = lane & 15;
    f32x4 acc[2][4];
    #pragma unroll
    for (int i = 0; i < 2; ++i)
        #pragma unroll
        for (int j = 0; j < 4; ++j) acc[i][j] = (f32x4){0.f, 0.f, 0.f, 0.f};
    const ushort* g1tb = G1t + (size_t)b * 131072;

    for (int k0 = 0; k0 < 1024; k0 += 32) {
        __syncthreads();
        {
            int m = row0 + arow;
            float rm = (m < se) ? 1.f : 0.f;
            const float* lr_ = la + ((size_t)(b * MM + m)) * MM + k0 + ak;
            float4 a0 = *(const float4*)lr_;
            float4 a1 = *(const float4*)(lr_ + 4);
            float vv[8] = {a0.x,a0.y,a0.z,a0.w,a1.x,a1.y,a1.z,a1.w};
            s16x8 pa;
            #pragma unroll
            for (int e = 0; e < 8; ++e) {
                int j = k0 + ak + e;
                float cm = (j < se) ? 1.f : 0.f;
                float v = vv[e] * rm * cm + ((j == m) ? rm : 0.f);
                pa[e] = (short)f2b(v);
            }
            *(s16x8*)&As[arow * 32 + ak] = pa;
            *(s16x8*)&Bs[arow * 32 + ak] =
                *(const s16x8*)&g1tb[(size_t)arow * 1024 + k0 + ak];
            *(s16x8*)&Bs[(arow + 64) * 32 + ak] =
                *(const s16x8*)&g1tb[(size_t)(arow + 64) * 1024 + k0 + ak];
        }
        __syncthreads();
        s16x8 af[2], bfv[4];
        #pragma unroll
        for (int mi = 0; mi < 2; ++mi)
            af[mi] = *(const s16x8*)&As[(wr * 32 + mi * 16 + fr) * 32 + qk];
        #pragma unroll
        for (int ni = 0; ni < 4; ++ni)
            bfv[ni] = *(const s16x8*)&Bs[(wc * 64 + ni * 16 + fr) * 32 + qk];
        #pragma unroll
        for (int mi = 0; mi < 2; ++mi)
            #pragma unroll
            for (int ni = 0; ni < 4; ++ni)
                acc[mi][ni] = __builtin_amdgcn_mfma_f32_16x16x32_bf16(
                    af[mi], bfv[ni], acc[mi][ni], 0, 0, 0);
    }
    int crow = (lane >> 4) * 4;
    #pragma unroll
    for (int mi = 0; mi < 2; ++mi) {
        #pragma unroll
        for (int ni = 0; ni < 4; ++ni) {
            int gc   = wc * 64 + ni * 16 + fr;
            int lrow = wr * 32 + mi * 16 + crow;
            #pragma unroll
            for (int rg = 0; rg < 4; ++rg) {
                float g = fmaxf(acc[mi][ni][rg], 0.f);
                int node = srcs[lrow + rg];
                atomicAdd(&node_emb[(size_t)(b * NN + node) * 256 + 128 + gc], g);
            }
        }
    }
}

// ---------------------------------------------------------------- K6:
// hid = relu(ci @ W1cat + b1cat); ci A-tiles built in-staging from gathers:
//   k<256: node_emb[i0]+node_emb[i1] (agg half masked); k<384: relu(Xp0+Xp1);
//   else: ci2 (precomputed Q).
__global__ __launch_bounds__(256) void k6_mlp1(
    const float* __restrict__ node_emb, const float* __restrict__ Xp,
    const ushort* __restrict__ ci2, const ushort* __restrict__ W1t,
    const float* __restrict__ b1cat,
    const int* __restrict__ opair, const int* __restrict__ nobj,
    ushort* __restrict__ H)
{
    __shared__ ushort As[128 * 32];
    __shared__ ushort Bs[128 * 32];
    __shared__ int po0[128], po1[128], px0[128], px1[128];
    __shared__ float pn0[128], pn1[128];
    int t    = threadIdx.x;
    int col0 = blockIdx.x * 128;
    int row0 = blockIdx.y * 128;
    if (t < 128) {
        int r = row0 + t;
        int b = r >> 9, p = r & 511;
        int i0 = opair[(b * PP + p) * 2];
        int i1 = opair[(b * PP + p) * 2 + 1];
        int s  = nobj[b];
        po0[t] = (b * NN + i0) * 256;
        po1[t] = (b * NN + i1) * 256;
        px0[t] = (b * NN + i0) * 128;
        px1[t] = (b * NN + i1) * 128;
        pn0[t] = (i0 < s) ? 1.f : 0.f;
        pn1[t] = (i1 < s) ? 1.f : 0.f;
    }
    int lane = t & 63, w = t >> 6, wr = w >> 1, wc = w & 1;
    int arow = w * 32 + (lane >> 2);
    int ak   = (lane & 3) * 8;
    int qk   = (lane >> 4) * 8, fr = lane & 15;
    f32x4 acc[4][4];
    #pragma unroll
    for (int i = 0; i < 4; ++i)
        #pragma unroll
        for (int j = 0; j < 4; ++j) acc[i][j] = (f32x4){0.f, 0.f, 0.f, 0.f};

    for (int k0 = 0; k0 < 512; k0 += 32) {
        __syncthreads();
        #pragma unroll
        for (int rr = 0; rr < 2; ++rr) {
            int row = arow + rr * 16;
            s16x8 pk;
            if (k0 < 256) {
                const float* pa = node_emb + po0[row] + k0 + ak;
                const float* pb = node_emb + po1[row] + k0 + ak;
                float4 a0 = *(const float4*)pa, a1 = *(const float4*)(pa + 4);
                float4 b0 = *(const float4*)pb, b1 = *(const float4*)(pb + 4);
                float m0 = (k0 >= 128) ? pn0[row] : 1.f;
                float m1 = (k0 >= 128) ? pn1[row] : 1.f;
                pk[0]=f2b(a0.x*m0+b0.x*m1); pk[1]=f2b(a0.y*m0+b0.y*m1);
                pk[2]=f2b(a0.z*m0+b0.z*m1); pk[3]=f2b(a0.w*m0+b0.w*m1);
                pk[4]=f2b(a1.x*m0+b1.x*m1); pk[5]=f2b(a1.y*m0+b1.y*m1);
                pk[6]=f2b(a1.z*m0+b1.z*m1); pk[7]=f2b(a1.w*m0+b1.w*m1);
            } else if (k0 < 384) {
                int kk = k0 - 256 + ak;
                const float* pa = Xp + px0[row] + kk;
                const float* pb = Xp + px1[row] + kk;
                float4 a0 = *(const float4*)pa, a1 = *(const float4*)(pa + 4);
                float4 b0 = *(const float4*)pb, b1 = *(const float4*)(pb + 4);
                pk[0]=f2b(fmaxf(a0.x+b0.x,0.f)); pk[1]=f2b(fmaxf(a0.y+b0.y,0.f));
                pk[2]=f2b(fmaxf(a0.z+b0.z,0.f)); pk[3]=f2b(fmaxf(a0.w+b0.w,0.f));
                pk[4]=f2b(fmaxf(a1.x+b1.x,0.f)); pk[5]=f2b(fmaxf(a1.y+b1.y,0.f));
                pk[6]=f2b(fmaxf(a1.z+b1.z,0.f)); pk[7]=f2b(fmaxf(a1.w+b1.w,0.f));
            } else {
                int kk = k0 - 384 + ak;
                pk = *(const s16x8*)&ci2[(size_t)(row0 + row) * 128 + kk];
            }
            *(s16x8*)&As[row * 32 + ak] = pk;
        }
        *(s16x8*)&Bs[arow * 32 + ak] =
            *(const s16x8*)&W1t[(size_t)(col0 + arow) * 512 + k0 + ak];
        *(s16x8*)&Bs[(arow + 16) * 32 + ak] =
            *(const s16x8*)&W1t[(size_t)(col0 + arow + 16) * 512 + k0 + ak];
        __syncthreads();
        s16x8 af[4], bfv[4];
        #pragma unroll
        for (int mi = 0; mi < 4; ++mi)
            af[mi] = *(const s16x8*)&As[(wr * 64 + mi * 16 + fr) * 32 + qk];
        #pragma unroll
        for (int ni = 0; ni < 4; ++ni)
            bfv[ni] = *(const s16x8*)&Bs[(wc * 64 + ni * 16 + fr) * 32 + qk];
        #pragma unroll
        for (int mi = 0; mi < 4; ++mi)
            #pragma unroll
            for (int ni = 0; ni < 4; ++ni)
                acc[mi][ni] = __builtin_amdgcn_mfma_f32_16x16x32_bf16(
                    af[mi], bfv[ni], acc[mi][ni], 0, 0, 0);
    }
    int crow = (lane >> 4) * 4;
    #pragma unroll
    for (int mi = 0; mi < 4; ++mi) {
        #pragma unroll
        for (int ni = 0; ni < 4; ++ni) {
            int gc = col0 + wc * 64 + ni * 16 + fr;
            int gr = row0 + wr * 64 + mi * 16 + crow;
            float bias = b1cat[gc];
            #pragma unroll
            for (int rg = 0; rg < 4; ++rg)
                H[(size_t)(gr + rg) * 768 + gc] =
                    f2b(fmaxf(acc[mi][ni][rg] + bias, 0.f));
        }
    }
}

// ---------------------------------------------------------------- K8:
// out = H @ W2cat + b2cat (block-diag W2cat routes the 3 heads).
// M=64/block, N=32, K=768.
__global__ __launch_bounds__(256) void k8_mlp2(
    const ushort* __restrict__ H, const ushort* __restrict__ W2catB,
    const float* __restrict__ b2cat, float* __restrict__ outp)
{
    __shared__ ushort As[64 * 32];
    __shared__ ushort Bs[32 * 32];
    int t = threadIdx.x;
    int row0 = blockIdx.x * 64;
    int lane = t & 63, w = t >> 6;
    int arow = t >> 2;          // 0..63
    int ak   = (t & 3) * 8;
    int qk   = (lane >> 4) * 8, fr = lane & 15;
    f32x4 acc[2];
    acc[0] = (f32x4){0.f,0.f,0.f,0.f};
    acc[1] = (f32x4){0.f,0.f,0.f,0.f};
    for (int k0 = 0; k0 < 768; k0 += 32) {
        __syncthreads();
        *(s16x8*)&As[arow * 32 + ak] =
            *(const s16x8*)&H[(size_t)(row0 + arow) * 768 + k0 + ak];
        if (t < 128) {
            int br = t >> 2;
            *(s16x8*)&Bs[br * 32 + ((t & 3) * 8)] =
                *(const s16x8*)&W2catB[(size_t)br * 768 + k0 + (t & 3) * 8];
        }
        __syncthreads();
        s16x8 af = *(const s16x8*)&As[(w * 16 + fr) * 32 + qk];
        s16x8 b0 = *(const s16x8*)&Bs[fr * 32 + qk];
        s16x8 b1 = *(const s16x8*)&Bs[(16 + fr) * 32 + qk];
        acc[0] = __builtin_amdgcn_mfma_f32_16x16x32_bf16(af, b0, acc[0], 0, 0, 0);
        acc[1] = __builtin_amdgcn_mfma_f32_16x16x32_bf16(af, b1, acc[1], 0, 0, 0);
    }
    int crow = (lane >> 4) * 4;
    #pragma unroll
    for (int ni = 0; ni < 2; ++ni) {
        int o = ni * 16 + fr;
        float bias = b2cat[o];
        int gr = row0 + w * 16 + crow;
        #pragma unroll
        for (int rg = 0; rg < 4; ++rg) {
            float v = acc[ni][rg] + bias;
            int p = gr + rg;
            if (o < 9)       outp[(size_t)p * 9 + o] = v;
            else if (o < 15) outp[8192 * 9 + (size_t)p * 6 + (o - 9)] = v;
            else             outp[8192 * 15 + (size_t)p * 17 + (o - 15)] = v;
        }
    }
}

// ----------------------------------------------------------------
extern "C" void kernel_launch(void* const* d_in, const int* in_sizes, int n_in,
                              void* d_out, int out_size, void* d_ws, size_t ws_size,
                              hipStream_t stream) {
    const float* nf    = (const float*)d_in[0];
    const float* ef    = (const float*)d_in[1];
    const float* adj   = (const float*)d_in[2];
    const float* la    = (const float*)d_in[3];
    const int*   eidx  = (const int*)d_in[4];
    const int*   opair = (const int*)d_in[5];
    const int*   nobj  = (const int*)d_in[6];
    const int*   nedg  = (const int*)d_in[7];
    const float* Wn    = (const float*)d_in[8];
    const float* We    = (const float*)d_in[9];
    const float* Wn2   = (const float*)d_in[10];
    const float* We2   = (const float*)d_in[11];
    const float* scrW1 = (const float*)d_in[12];
    const float* scrb1 = (const float*)d_in[13];
    const float* scrW2 = (const float*)d_in[14];
    const float* scrb2 = (const float*)d_in[15];
    const float* lrW1  = (const float*)d_in[16];
    const float* lrb1  = (const float*)d_in[17];
    const float* lrW2  = (const float*)d_in[18];
    const float* lrb2  = (const float*)d_in[19];
    const float* mrW1  = (const float*)d_in[20];
    const float* mrb1  = (const float*)d_in[21];
    const float* mrW2  = (const float*)d_in[22];
    const float* mrb2  = (const float*)d_in[23];

    float* ws = (float*)d_ws;
    float*  Xp       = ws;                               // 262144 f32
    float*  node_emb = ws + 262144;                      // 524288 f32
    ushort* Yt       = (ushort*)(ws + 786432);           // 262144 u16
    ushort* G1t      = (ushort*)(ws + 917504);           // 2097152 u16
    ushort* ci2      = (ushort*)(ws + 1966080);          // 1048576 u16
    ushort* H        = (ushort*)(ws + 2490368);          // 6291456 u16
    ushort* W1t      = (ushort*)(ws + 5636096);          // 393216 u16
    ushort* WncT     = (ushort*)(ws + 5832704);          // 131072 u16
    ushort* WeT      = (ushort*)(ws + 5898240);          // 32768 u16
    ushort* We2T     = (ushort*)(ws + 5914624);          // 32768 u16
    ushort* W2catB   = (ushort*)(ws + 5931008);          // 24576 u16
    float*  b1cat    = ws + 5943296;                     // 768
    float*  b2cat    = ws + 5944064;                     // 32

    k0_prep<<<1314, 256, 0, stream>>>(lrW1, scrW1, mrW1, lrb1, scrb1, mrb1,
                                      Wn, Wn2, We, We2,
                                      lrW2, scrW2, mrW2, lrb2, scrb2, mrb2,
                                      W1t, WncT, WeT, We2T, W2catB, b1cat, b2cat);
    fproj  <<<224, 256, 0, stream>>>(nf, ef, eidx, opair, nobj, nedg,
                                     WncT, WeT, We2T, Yt, Xp, G1t, ci2);
    k2m_gcn<<<BB, 256, 0, stream>>>(adj, nobj, Yt, node_emb);
    lgemm  <<<BB * 16, 256, 0, stream>>>(la, G1t, eidx, nedg, node_emb);
    k6_mlp1<<<dim3(6, 64), 256, 0, stream>>>(node_emb, Xp, ci2, W1t, b1cat,
                                             opair, nobj, H);
    k8_mlp2<<<128, 256, 0, stream>>>(H, W2catB, b2cat, (float*)d_out);
}